// Round 1
// baseline (14687.886 us; speedup 1.0000x reference)
//
#include <hip/hip_runtime.h>
#include <hip/hip_bf16.h>
#include <cstdint>
#include <cstddef>

// ============================================================================
// BiSLSTM (B=32, S=1024, E=256, H=256, K=2), fp32 in/out.
//
// Structure:
//   kernel 1 (prepass): transpose+convert Wx/Ws/Wrx/Wrh -> bf16 "B^T" layout
//       in d_ws; zero h/s exchange buffers and barrier counters.
//   kernel 2 (bislstm): persistent grid, 64 WGs x 256 threads.
//       WG -> (direction d = bid>>5, unit-group g = bid&31; units [8g,8g+8)).
//       Per step: z = [h|s]@[Wh|Ws] + x@Wx (MFMA 16x16x32 bf16, fp32 acc)
//       -> gates -> c,h (fp32 state in LDS) -> publish h (agent atomics)
//       -> BARRIER A -> r = sigmoid(x@Wrx + h@Wrh + br) -> s update
//       -> publish s[idx] -> BARRIER B.
//       Two device barriers per step is structural (z->h->r->s chain).
//   Cross-WG data exclusively via agent-scope atomics (coherent point; no
//   L2 writeback fences needed for data). Barriers: per-direction monotonic
//   counter, release-add + relaxed spin + single acquire load.
//
// ws usage: ~3.2 MB. LDS: ~63.5 KB/WG (<=64KB).
// ============================================================================

typedef __bf16 bf16x8 __attribute__((ext_vector_type(8)));
typedef float  f32x4  __attribute__((ext_vector_type(4)));

#define DEVINL __device__ __forceinline__

constexpr int Bb = 32, Ss = 1024;
constexpr int NWG = 32;              // WGs per direction

// ---- ws layout (bytes) ----
constexpr size_t OFF_CTR = 0;                         // 2 counters, 256B apart
constexpr size_t OFF_H   = 1024;                      // [2 parity][2 dir][32][256] bf16
constexpr size_t SZ_HS   = (size_t)2*2*32*256*2;      // 65536
constexpr size_t OFF_S   = OFF_H + SZ_HS;
constexpr size_t OFF_WX  = OFF_S + SZ_HS;             // [2][1024 col][256 k] bf16
constexpr size_t SZ_W    = (size_t)2*1024*256*2;      // 1 MB
constexpr size_t OFF_WS  = OFF_WX + SZ_W;
constexpr size_t OFF_WRX = OFF_WS + SZ_W;             // [2][2][256 j][256 k] bf16
constexpr size_t SZ_WR   = (size_t)2*2*256*256*2;     // 512 KB
constexpr size_t OFF_WRH = OFF_WRX + SZ_WR;           // end ~3.2MB

DEVINL unsigned short f2bf(float f) {                 // RNE fp32->bf16
    unsigned u = __builtin_bit_cast(unsigned, f);
    u += 0x7FFFu + ((u >> 16) & 1u);
    return (unsigned short)(u >> 16);
}
DEVINL float sigm(float x) { return 1.f / (1.f + __expf(-x)); }

// ---------------------------------------------------------------------------
__global__ void prepass(const float* __restrict__ Wx0, const float* __restrict__ Ws0,
                        const float* __restrict__ Wx1, const float* __restrict__ Ws1,
                        const float* __restrict__ Wrx0, const float* __restrict__ Wrh0,
                        const float* __restrict__ Wrx1, const float* __restrict__ Wrh1,
                        unsigned char* __restrict__ ws)
{
    unsigned short* wxT  = (unsigned short*)(ws + OFF_WX);
    unsigned short* wsT  = (unsigned short*)(ws + OFF_WS);
    unsigned short* wrxT = (unsigned short*)(ws + OFF_WRX);
    unsigned short* wrhT = (unsigned short*)(ws + OFF_WRH);
    int tid = blockIdx.x * blockDim.x + threadIdx.x;
    int NT  = gridDim.x * blockDim.x;
    // WxT/WsT: [d][n][k] = W[k*1024+n]
    for (int e = tid; e < 2*1024*256; e += NT) {
        int d = e >> 18, r = e & 262143, n = r >> 8, k = r & 255;
        const float* wx = d ? Wx1 : Wx0;
        const float* wz = d ? Ws1 : Ws0;
        wxT[e] = f2bf(wx[k*1024 + n]);
        wsT[e] = f2bf(wz[k*1024 + n]);
    }
    // WrxT/WrhT: [d][kk][j][k] = W[(kk*256+k)*256+j]
    for (int e = tid; e < 2*2*256*256; e += NT) {
        int d = e >> 17, r = e & 131071, kk = r >> 16, r2 = r & 65535;
        int j = r2 >> 8, k = r2 & 255;
        const float* wrx = d ? Wrx1 : Wrx0;
        const float* wrh = d ? Wrh1 : Wrh0;
        wrxT[e] = f2bf(wrx[(kk*256 + k)*256 + j]);
        wrhT[e] = f2bf(wrh[(kk*256 + k)*256 + j]);
    }
    // zero Hbuf+Sbuf and barrier counters (ws is poisoned 0xAA each launch)
    unsigned* z = (unsigned*)(ws + OFF_H);
    for (int e = tid; e < (int)(2*SZ_HS/4); e += NT) z[e] = 0u;
    if (tid < 256) ((unsigned*)ws)[tid] = 0u;
}

// ---------------------------------------------------------------------------
__launch_bounds__(256, 1)
__global__ void bislstm(const float* __restrict__ inputs, const float* __restrict__ mask,
                        const float* __restrict__ Wh0, const float* __restrict__ Wh1,
                        const float* __restrict__ b0,  const float* __restrict__ b1,
                        const float* __restrict__ br0, const float* __restrict__ br1,
                        const int* __restrict__ idxp,
                        unsigned char* __restrict__ ws, float* __restrict__ out)
{
    const int bid = blockIdx.x;
    const int d   = bid >> 5;          // direction
    const int g   = bid & 31;          // unit group (units 8g..8g+7)
    const int tid = threadIdx.x;
    const int wave = tid >> 6, lane = tid & 63;
    const int lm = lane & 15, lq = lane >> 4;

    // ---- LDS (total ~63.5 KB) ----
    __shared__ __align__(16) unsigned short sWh[32][264];  // Wh^T slice [n_l][k]
    __shared__ __align__(16) unsigned short sA[32][520];   // A staging [b][k0..511]
    __shared__ float zs[2][32][16];                        // z per N-tile
    __shared__ float rsx[32][16], rsh[32][16];             // r partials
    __shared__ float sC[32][8], sH[32][8], sS[2][32][8];   // fp32 state
    __shared__ unsigned short sHb[256], sSb[256];          // publish staging

    const float* Whd = d ? Wh1 : Wh0;
    const float* bd  = d ? b1  : b0;
    const float* brd = d ? br1 : br0;
    const unsigned short* wxT  = (const unsigned short*)(ws + OFF_WX)  + (size_t)d*1024*256;
    const unsigned short* wsT  = (const unsigned short*)(ws + OFF_WS)  + (size_t)d*1024*256;
    const unsigned short* wrxT = (const unsigned short*)(ws + OFF_WRX) + (size_t)d*2*256*256;
    const unsigned short* wrhT = (const unsigned short*)(ws + OFF_WRH) + (size_t)d*2*256*256;
    unsigned long long* Hbuf = (unsigned long long*)(ws + OFF_H);      // [p][d] blocks of 2048 u64
    unsigned long long* Sbuf = (unsigned long long*)(ws + OFF_S);
    unsigned* ctr = (unsigned*)(ws + OFF_CTR) + (size_t)d*64;          // 256B apart per dir
    const int idxv = idxp[0];

    // ---- load Wh slice -> LDS (one time), transposed, bf16 ----
    for (int i = 0; i < 32; ++i) {
        int e = tid + 256*i, k = e >> 5, nl = e & 31;
        int col = (nl >> 3)*256 + g*8 + (nl & 7);
        sWh[nl][k] = f2bf(Whd[(size_t)k*1024 + col]);
    }
    // ---- zero state ----
    {
        int b_ = tid >> 3, j = tid & 7;
        sC[b_][j] = 0.f; sH[b_][j] = 0.f; sS[0][b_][j] = 0.f; sS[1][b_][j] = 0.f;
    }
    __syncthreads();

    // per-thread elementwise cell + constants
    const int eb = tid >> 3, ej = tid & 7;
    const int gj = g*8 + ej;
    const float bias_i = bd[gj], bias_f = bd[256+gj], bias_g = bd[512+gj], bias_o = bd[768+gj];
    const float brr0 = brd[gj], brr1 = brd[256+gj];

    // MFMA tile roles
    const int zMt = wave & 1, zNt = wave >> 1;
    const int znl = zNt*16 + lm;
    const int zcol = (znl >> 3)*256 + g*8 + (znl & 7);     // global z-column
    const int rMt = wave & 1;                               // r M-tile
    const int rks = lm >> 3;                                // r share index
    const int rj  = g*8 + (lm & 7);                         // r hidden col

    unsigned tgt = 0;
#define GRID_BARRIER()                                                          \
    do {                                                                        \
        __syncthreads();                                                        \
        if (tid == 0) {                                                         \
            __hip_atomic_fetch_add(ctr, 1u, __ATOMIC_RELEASE,                   \
                                   __HIP_MEMORY_SCOPE_AGENT);                   \
            while (__hip_atomic_load(ctr, __ATOMIC_RELAXED,                     \
                                     __HIP_MEMORY_SCOPE_AGENT) < tgt)           \
                __builtin_amdgcn_s_sleep(1);                                    \
            (void)__hip_atomic_load(ctr, __ATOMIC_ACQUIRE,                      \
                                    __HIP_MEMORY_SCOPE_AGENT);                  \
        }                                                                       \
        __syncthreads();                                                        \
    } while (0)

    for (int t = 0; t < Ss; ++t) {
        const int tx = d ? (Ss - 1 - t) : t;
        const int pp = (t + 1) & 1;        // prev parity (zeros at t=0)
        const int pc = t & 1;              // cur parity

        // ---- stage h_{t-1} (cols 0..255) and s_{t-1}[idx] (cols 256..511) ----
        {
            const unsigned long long* hsrc = Hbuf + (size_t)(pp*2 + d)*2048;
            const unsigned long long* ssrc = Sbuf + (size_t)(pp*2 + d)*2048;
#pragma unroll
            for (int i = 0; i < 8; ++i) {
                int e = tid + 256*i;
                int b_ = e >> 6, u4 = e & 63;
                unsigned long long hv = __hip_atomic_load(hsrc + e, __ATOMIC_RELAXED, __HIP_MEMORY_SCOPE_AGENT);
                unsigned long long sv = __hip_atomic_load(ssrc + e, __ATOMIC_RELAXED, __HIP_MEMORY_SCOPE_AGENT);
                *(unsigned long long*)&sA[b_][u4*4]       = hv;
                *(unsigned long long*)&sA[b_][256 + u4*4] = sv;
            }
        }
        __syncthreads();

        // ---- z: h-part (LDS Wh) + s-part (streamed Ws) ----
        f32x4 acc0 = {0.f, 0.f, 0.f, 0.f};
        {
            bf16x8 wsf[8];
#pragma unroll
            for (int kt = 0; kt < 8; ++kt)
                wsf[kt] = *(const bf16x8*)(wsT + (size_t)zcol*256 + 32*kt + 8*lq);
#pragma unroll
            for (int kt = 0; kt < 16; ++kt) {
                bf16x8 a = *(const bf16x8*)&sA[zMt*16 + lm][32*kt + 8*lq];
                bf16x8 bb = (kt < 8) ? *(const bf16x8*)&sWh[znl][32*kt + 8*lq] : wsf[kt - 8];
                acc0 = __builtin_amdgcn_mfma_f32_16x16x32_bf16(a, bb, acc0, 0, 0, 0);
            }
        }
        __syncthreads();   // h/s consumed; overlay x into cols 0..255

        // ---- stage x_t (fp32->bf16) ----
        {
#pragma unroll
            for (int i = 0; i < 8; ++i) {
                int e = tid + 256*i;
                int b_ = e >> 6, c4 = e & 63;
                float4 v = *(const float4*)(inputs + (((size_t)b_*Ss + tx) << 8) + c4*4);
                unsigned long long pk = (unsigned long long)f2bf(v.x)
                                      | ((unsigned long long)f2bf(v.y) << 16)
                                      | ((unsigned long long)f2bf(v.z) << 32)
                                      | ((unsigned long long)f2bf(v.w) << 48);
                *(unsigned long long*)&sA[b_][c4*4] = pk;
            }
        }
        __syncthreads();

        // ---- z: x-part (streamed Wx) ----
        {
            bf16x8 wxf[8];
#pragma unroll
            for (int kt = 0; kt < 8; ++kt)
                wxf[kt] = *(const bf16x8*)(wxT + (size_t)zcol*256 + 32*kt + 8*lq);
#pragma unroll
            for (int kt = 0; kt < 8; ++kt) {
                bf16x8 a = *(const bf16x8*)&sA[zMt*16 + lm][32*kt + 8*lq];
                acc0 = __builtin_amdgcn_mfma_f32_16x16x32_bf16(a, wxf[kt], acc0, 0, 0, 0);
            }
        }
#pragma unroll
        for (int r = 0; r < 4; ++r)
            zs[zNt][zMt*16 + lq*4 + r][lm] = acc0[r];
        __syncthreads();

        // ---- gates -> c,h (fp32), publish h ----
        float m_, cu_, hu_;
        {
            float zi = zs[0][eb][ej]   + bias_i;
            float zf = zs[0][eb][8+ej] + bias_f;
            float zg = zs[1][eb][ej]   + bias_g;
            float zo = zs[1][eb][8+ej] + bias_o;
            float co = sC[eb][ej], ho = sH[eb][ej];
            float cn = sigm(zf)*co + sigm(zi)*tanhf(zg);
            float hn = sigm(zo)*tanhf(cn);
            m_  = mask[(size_t)eb*Ss + tx];
            cu_ = m_*cn + (1.f - m_)*co;
            hu_ = m_*hn + (1.f - m_)*ho;
            sC[eb][ej] = cu_; sH[eb][ej] = hu_;
            sHb[eb*8 + ej] = f2bf(hu_);
            out[((size_t)tx*32 + eb)*512 + d*256 + gj] = hu_;
            out[16777216 + ((size_t)tx*32 + eb)*512 + d*256 + gj] = cu_;
        }
        __syncthreads();
        if (wave == 0) {
            unsigned long long pk = *(unsigned long long*)&sHb[lane*4];
            int b_ = lane >> 1, half = lane & 1;
            size_t di = (size_t)(pc*2 + d)*2048 + (size_t)b_*64 + g*2 + half;
            __hip_atomic_store(Hbuf + di, pk, __ATOMIC_RELAXED, __HIP_MEMORY_SCOPE_AGENT);
        }
        tgt += NWG; GRID_BARRIER();   // ---- barrier A: h_t complete ----

        // ---- r: x-part (waves 0,1; sA cols 0..255 still hold x) ----
        if (wave < 2) {
            f32x4 racc = {0.f, 0.f, 0.f, 0.f};
            bf16x8 wf[8];
#pragma unroll
            for (int kt = 0; kt < 8; ++kt)
                wf[kt] = *(const bf16x8*)(wrxT + (size_t)(rks*256 + rj)*256 + 32*kt + 8*lq);
#pragma unroll
            for (int kt = 0; kt < 8; ++kt) {
                bf16x8 a = *(const bf16x8*)&sA[rMt*16 + lm][32*kt + 8*lq];
                racc = __builtin_amdgcn_mfma_f32_16x16x32_bf16(a, wf[kt], racc, 0, 0, 0);
            }
#pragma unroll
            for (int r = 0; r < 4; ++r)
                rsx[rMt*16 + lq*4 + r][lm] = racc[r];
        }
        __syncthreads();   // x consumed -> overlay h_t into cols 256..511

        {
            const unsigned long long* hsrc = Hbuf + (size_t)(pc*2 + d)*2048;
#pragma unroll
            for (int i = 0; i < 8; ++i) {
                int e = tid + 256*i;
                int b_ = e >> 6, u4 = e & 63;
                unsigned long long hv = __hip_atomic_load(hsrc + e, __ATOMIC_RELAXED, __HIP_MEMORY_SCOPE_AGENT);
                *(unsigned long long*)&sA[b_][256 + u4*4] = hv;
            }
        }
        __syncthreads();

        // ---- r: h-part (waves 2,3) ----
        if (wave >= 2) {
            f32x4 rh = {0.f, 0.f, 0.f, 0.f};
            bf16x8 wf[8];
#pragma unroll
            for (int kt = 0; kt < 8; ++kt)
                wf[kt] = *(const bf16x8*)(wrhT + (size_t)(rks*256 + rj)*256 + 32*kt + 8*lq);
#pragma unroll
            for (int kt = 0; kt < 8; ++kt) {
                bf16x8 a = *(const bf16x8*)&sA[rMt*16 + lm][256 + 32*kt + 8*lq];
                rh = __builtin_amdgcn_mfma_f32_16x16x32_bf16(a, wf[kt], rh, 0, 0, 0);
            }
#pragma unroll
            for (int r = 0; r < 4; ++r)
                rsh[rMt*16 + lq*4 + r][lm] = rh[r];
        }
        __syncthreads();

        // ---- s update, publish s[idx] ----
        {
#pragma unroll
            for (int kk = 0; kk < 2; ++kk) {
                float rv = rsx[eb][kk*8+ej] + rsh[eb][kk*8+ej] + (kk ? brr1 : brr0);
                float rr = sigm(rv);
                float so = sS[kk][eb][ej];
                float sn = rr*so + (1.f - rr)*cu_;
                float su = m_*sn + (1.f - m_)*so;
                sS[kk][eb][ej] = su;
                out[33554432 + (((size_t)kk*1024 + tx)*32 + eb)*512 + d*256 + gj] = su;
                if (kk == idxv) sSb[eb*8 + ej] = f2bf(su);
            }
        }
        __syncthreads();
        if (wave == 0) {
            unsigned long long pk = *(unsigned long long*)&sSb[lane*4];
            int b_ = lane >> 1, half = lane & 1;
            size_t di = (size_t)(pc*2 + d)*2048 + (size_t)b_*64 + g*2 + half;
            __hip_atomic_store(Sbuf + di, pk, __ATOMIC_RELAXED, __HIP_MEMORY_SCOPE_AGENT);
        }
        tgt += NWG; GRID_BARRIER();   // ---- barrier B: s_t[idx] complete ----
    }
#undef GRID_BARRIER
}

// ---------------------------------------------------------------------------
extern "C" void kernel_launch(void* const* d_in, const int* in_sizes, int n_in,
                              void* d_out, int out_size, void* d_ws, size_t ws_size,
                              hipStream_t stream) {
    const float* inputs = (const float*)d_in[0];
    const float* mask_  = (const float*)d_in[1];
    const float* Wx0  = (const float*)d_in[2];
    const float* Wh0  = (const float*)d_in[3];
    const float* Ws0  = (const float*)d_in[4];
    const float* b0   = (const float*)d_in[5];
    const float* Wrx0 = (const float*)d_in[6];
    const float* Wrh0 = (const float*)d_in[7];
    const float* br0  = (const float*)d_in[8];
    const float* Wx1  = (const float*)d_in[9];
    const float* Wh1  = (const float*)d_in[10];
    const float* Ws1  = (const float*)d_in[11];
    const float* b1   = (const float*)d_in[12];
    const float* Wrx1 = (const float*)d_in[13];
    const float* Wrh1 = (const float*)d_in[14];
    const float* br1  = (const float*)d_in[15];
    const int*   idxp = (const int*)d_in[16];
    unsigned char* ws = (unsigned char*)d_ws;

    hipLaunchKernelGGL(prepass, dim3(512), dim3(256), 0, stream,
                       Wx0, Ws0, Wx1, Ws1, Wrx0, Wrh0, Wrx1, Wrh1, ws);
    // 64 WGs (32/dir), 1 WG/CU max by LDS; all co-resident on 256 CUs.
    hipLaunchKernelGGL(bislstm, dim3(64), dim3(256), 0, stream,
                       inputs, mask_, Wh0, Wh1, b0, b1, br0, br1, idxp,
                       ws, (float*)d_out);
}

// Round 2
// 11993.908 us; speedup vs baseline: 1.2246x; 1.2246x over previous
//
#include <hip/hip_runtime.h>
#include <hip/hip_bf16.h>
#include <cstdint>
#include <cstddef>

// ============================================================================
// BiSLSTM (B=32, S=1024, E=256, H=256, K=2), fp32 in/out.  Round 2.
//
// R1 was latency-bound (MfmaUtil 0.4%, VALUBusy 1%): ~7us per grid barrier
// (RMW contention on one line + release/acquire cache maintenance).
// R2 restructure:
//   * producer->consumer FLAGS instead of barriers: each WG stores its own
//     flag word (relaxed agent atomic) after an explicit s_waitcnt vmcnt(0);
//     consumers poll 32 flags relaxed. No fetch_add, no wbl2/inv.
//   * all weight fragments preloaded into VGPRs (~128 VGPR/thread); prepass
//     pre-transposes Wh too.
//   * LDS A-operand staged directly in MFMA fragment order: ds_read_b128 of
//     consecutive 16B/lane (conflict-free); stage writes spread across banks.
//   * waits overlapped: r x-part + x_{t+1} staging run inside the h/s
//     propagation windows.
// ============================================================================

typedef __bf16 bf16x8 __attribute__((ext_vector_type(8)));
typedef float  f32x4  __attribute__((ext_vector_type(4)));
typedef unsigned long long u64x2 __attribute__((ext_vector_type(2)));

#define DEVINL __device__ __forceinline__

constexpr int Ss = 1024;

// ---- ws layout (bytes) ----
constexpr size_t OFF_FLAGS = 0;                       // 1 KB: flagsH d0,d1 @0,256; flagsS @512,768
constexpr size_t OFF_H   = 1024;                      // [2 parity][2 dir][32 b][64 u64]
constexpr size_t SZ_HS   = (size_t)2*2*32*512;        // 65536
constexpr size_t OFF_S   = OFF_H + SZ_HS;
constexpr size_t OFF_WH  = OFF_S + SZ_HS;             // [2][1024 col][256 k] bf16
constexpr size_t SZ_W    = (size_t)2*1024*256*2;      // 1 MB
constexpr size_t OFF_WX  = OFF_WH + SZ_W;
constexpr size_t OFF_WS  = OFF_WX + SZ_W;
constexpr size_t OFF_WRX = OFF_WS + SZ_W;             // [2][2*256 j][256 k] bf16
constexpr size_t SZ_WR   = (size_t)2*2*256*256*2;     // 512 KB
constexpr size_t OFF_WRH = OFF_WRX + SZ_WR;           // end ~4.33 MB

DEVINL unsigned short f2bf(float f) {                 // RNE fp32->bf16
    unsigned u = __builtin_bit_cast(unsigned, f);
    u += 0x7FFFu + ((u >> 16) & 1u);
    return (unsigned short)(u >> 16);
}
DEVINL unsigned long long pack4(float4 v) {
    return (unsigned long long)f2bf(v.x) | ((unsigned long long)f2bf(v.y) << 16)
         | ((unsigned long long)f2bf(v.z) << 32) | ((unsigned long long)f2bf(v.w) << 48);
}
DEVINL float sigm(float x) { return 1.f / (1.f + __expf(-x)); }

// ---------------------------------------------------------------------------
__global__ void prepass(const float* __restrict__ Wx0, const float* __restrict__ Wh0,
                        const float* __restrict__ Ws0,
                        const float* __restrict__ Wx1, const float* __restrict__ Wh1,
                        const float* __restrict__ Ws1,
                        const float* __restrict__ Wrx0, const float* __restrict__ Wrh0,
                        const float* __restrict__ Wrx1, const float* __restrict__ Wrh1,
                        unsigned char* __restrict__ ws)
{
    unsigned short* whT  = (unsigned short*)(ws + OFF_WH);
    unsigned short* wxT  = (unsigned short*)(ws + OFF_WX);
    unsigned short* wsT  = (unsigned short*)(ws + OFF_WS);
    unsigned short* wrxT = (unsigned short*)(ws + OFF_WRX);
    unsigned short* wrhT = (unsigned short*)(ws + OFF_WRH);
    int tid = blockIdx.x * blockDim.x + threadIdx.x;
    int NT  = gridDim.x * blockDim.x;
    // [d][n][k] = W[k*1024+n]
    for (int e = tid; e < 2*1024*256; e += NT) {
        int d = e >> 18, r = e & 262143, n = r >> 8, k = r & 255;
        whT[e] = f2bf((d ? Wh1 : Wh0)[k*1024 + n]);
        wxT[e] = f2bf((d ? Wx1 : Wx0)[k*1024 + n]);
        wsT[e] = f2bf((d ? Ws1 : Ws0)[k*1024 + n]);
    }
    // [d][kk*256+j][k] = W[(kk*256+k)*256+j]
    for (int e = tid; e < 2*2*256*256; e += NT) {
        int d = e >> 17, r = e & 131071, kk = r >> 16, r2 = r & 65535;
        int j = r2 >> 8, k = r2 & 255;
        wrxT[e] = f2bf((d ? Wrx1 : Wrx0)[(kk*256 + k)*256 + j]);
        wrhT[e] = f2bf((d ? Wrh1 : Wrh0)[(kk*256 + k)*256 + j]);
    }
    // zero flags (ws poisoned 0xAA each launch)
    if (blockIdx.x == 0 && threadIdx.x < 256) ((unsigned*)ws)[threadIdx.x] = 0u;
}

// ---------------------------------------------------------------------------
// sA fragment layout: idx16(Mt,kt,lq,m) = ((Mt*24+kt)*4+lq)*16 + m   (16B units)
//   kt 0..7 = h (K 0..255), 8..15 = s, 16..23 = x.
#define FRAG_PTR(Mt,kt,lqv,m) \
    ((unsigned long long*)(sA + (size_t)(((((Mt)*24+(kt))*4+(lqv))*16+(m))*8)))

__launch_bounds__(256, 1)
__global__ void bislstm(const float* __restrict__ inputs, const float* __restrict__ mask,
                        const float* __restrict__ b0,  const float* __restrict__ b1,
                        const float* __restrict__ br0, const float* __restrict__ br1,
                        const int* __restrict__ idxp,
                        unsigned char* __restrict__ ws, float* __restrict__ out)
{
    const int bid = blockIdx.x;
    const int d   = bid >> 5;          // direction
    const int g   = bid & 31;          // unit group (units 8g..8g+7)
    const int tid = threadIdx.x;
    const int wave = tid >> 6, lane = tid & 63;
    const int lm = lane & 15, lq = lane >> 4;

    __shared__ __align__(16) unsigned short sA[24576];      // 48 KB frag-order A
    __shared__ float zs[2][32][16];
    __shared__ float rsx[32][16], rsh[32][16];
    __shared__ float sC[32][8], sHs[32][8], sS2[2][32][8];
    __shared__ __align__(8) unsigned short sHb[256], sSb[256];

    const unsigned short* whT  = (const unsigned short*)(ws + OFF_WH)  + (size_t)d*1024*256;
    const unsigned short* wxT  = (const unsigned short*)(ws + OFF_WX)  + (size_t)d*1024*256;
    const unsigned short* wsT  = (const unsigned short*)(ws + OFF_WS)  + (size_t)d*1024*256;
    const unsigned short* wrxT = (const unsigned short*)(ws + OFF_WRX) + (size_t)d*2*256*256;
    const unsigned short* wrhT = (const unsigned short*)(ws + OFF_WRH) + (size_t)d*2*256*256;
    unsigned long long* Hbuf = (unsigned long long*)(ws + OFF_H);
    unsigned long long* Sbuf = (unsigned long long*)(ws + OFF_S);
    unsigned* flagsH = (unsigned*)ws + d*64;
    unsigned* flagsS = (unsigned*)ws + 128 + d*64;
    const int idxv = idxp[0];
    const float* bd  = d ? b1  : b0;
    const float* brd = d ? br1 : br0;

    // roles
    const int zMt = wave & 1, zNt = wave >> 1;
    const int znl = zNt*16 + lm;
    const int zcol = (znl >> 3)*256 + g*8 + (znl & 7);     // global z-column
    const int rks = lm >> 3;
    const int rj  = g*8 + (lm & 7);

    // ---- preload all weight B-fragments into VGPRs ----
    bf16x8 whf[8], wsf[8], wxf[8], rwf[8];
#pragma unroll
    for (int kt = 0; kt < 8; ++kt) {
        whf[kt] = *(const bf16x8*)(whT + (size_t)zcol*256 + kt*32 + lq*8);
        wsf[kt] = *(const bf16x8*)(wsT + (size_t)zcol*256 + kt*32 + lq*8);
        wxf[kt] = *(const bf16x8*)(wxT + (size_t)zcol*256 + kt*32 + lq*8);
    }
    {
        const unsigned short* wrT = (wave < 2) ? wrxT : wrhT;
#pragma unroll
        for (int kt = 0; kt < 8; ++kt)
            rwf[kt] = *(const bf16x8*)(wrT + (size_t)(rks*256 + rj)*256 + kt*32 + lq*8);
    }

    // ---- zero h/s frag regions (kt<16) + state ----
    {
        unsigned long long* z8 = (unsigned long long*)sA;
#pragma unroll
        for (int i = 0; i < 16; ++i) {
            int r = tid + 256*i;                 // 4096 u64 over two Mt regions
            int u = (r & 2047) + (r >> 11)*3072; // Mt stride 3072 u64, zero first 2048
            z8[u] = 0ULL;
        }
        int b_ = tid >> 3, j = tid & 7;
        sC[b_][j] = 0.f; sHs[b_][j] = 0.f; sS2[0][b_][j] = 0.f; sS2[1][b_][j] = 0.f;
    }
    // ---- stage x_0 into x frag region ----
    {
        int tx0 = d ? (Ss - 1) : 0;
#pragma unroll
        for (int i = 0; i < 4; ++i) {
            int b_ = (tid & 7) + 8*i;
            int j  = tid >> 3;
            const float* xp = inputs + (((size_t)b_*Ss + tx0) << 8) + j*8;
            float4 v0 = *(const float4*)xp;
            float4 v1 = *(const float4*)(xp + 4);
            u64x2 pk; pk.x = pack4(v0); pk.y = pack4(v1);
            *(u64x2*)FRAG_PTR(b_ >> 4, 16 + (j >> 2), j & 3, b_ & 15) = pk;
        }
    }
    __syncthreads();

    // per-thread elementwise cell constants
    const int eb = tid >> 3, ej = tid & 7;
    const int gj = g*8 + ej;
    const float bias_i = bd[gj], bias_f = bd[256+gj], bias_g = bd[512+gj], bias_o = bd[768+gj];
    const float brr0 = brd[gj], brr1 = brd[256+gj];

    // A-frag base for this wave (consecutive 16B per lane -> conflict-free b128)
    const unsigned short* aBase = sA + (size_t)((zMt*96 + lq)*128 + lm*8);

    for (int t = 0; t < Ss; ++t) {
        const int tx = d ? (Ss - 1 - t) : t;
        const int pc = t & 1;
        const unsigned want = (unsigned)(t + 1);

        // ---- z = h@Wh + s@Ws + x@Wx ----
        f32x4 acc = {0.f, 0.f, 0.f, 0.f};
#pragma unroll
        for (int kt = 0; kt < 8; ++kt)
            acc = __builtin_amdgcn_mfma_f32_16x16x32_bf16(*(const bf16x8*)(aBase + kt*512), whf[kt], acc, 0, 0, 0);
#pragma unroll
        for (int kt = 0; kt < 8; ++kt)
            acc = __builtin_amdgcn_mfma_f32_16x16x32_bf16(*(const bf16x8*)(aBase + (8+kt)*512), wsf[kt], acc, 0, 0, 0);
#pragma unroll
        for (int kt = 0; kt < 8; ++kt)
            acc = __builtin_amdgcn_mfma_f32_16x16x32_bf16(*(const bf16x8*)(aBase + (16+kt)*512), wxf[kt], acc, 0, 0, 0);
#pragma unroll
        for (int r = 0; r < 4; ++r)
            zs[zNt][zMt*16 + lq*4 + r][lm] = acc[r];
        __syncthreads();                                   // S1

        // ---- gates -> c,h ----
        float m_, cu_, hu_;
        {
            float zi = zs[0][eb][ej]   + bias_i;
            float zf = zs[0][eb][8+ej] + bias_f;
            float zg = zs[1][eb][ej]   + bias_g;
            float zo = zs[1][eb][8+ej] + bias_o;
            float co = sC[eb][ej], ho = sHs[eb][ej];
            float cn = sigm(zf)*co + sigm(zi)*tanhf(zg);
            float hn = sigm(zo)*tanhf(cn);
            m_  = mask[(size_t)eb*Ss + tx];
            cu_ = m_*cn + (1.f - m_)*co;
            hu_ = m_*hn + (1.f - m_)*ho;
            sC[eb][ej] = cu_; sHs[eb][ej] = hu_;
            sHb[tid] = f2bf(hu_);
            out[((size_t)tx*32 + eb)*512 + d*256 + gj] = hu_;
            out[16777216 + ((size_t)tx*32 + eb)*512 + d*256 + gj] = cu_;
        }
        __syncthreads();                                   // S2

        // ---- publish h (wave0) ; rsx (waves0,1) ; poll flagsH (wave3) ----
        if (wave == 0) {
            unsigned long long pk = *(const unsigned long long*)&sHb[lane*4];
            __hip_atomic_store(Hbuf + (size_t)(pc*2 + d)*2048 + (size_t)(lane>>1)*64 + g*2 + (lane&1),
                               pk, __ATOMIC_RELAXED, __HIP_MEMORY_SCOPE_AGENT);
            asm volatile("s_waitcnt vmcnt(0)" ::: "memory");
            if (lane == 0)
                __hip_atomic_store(flagsH + g, want, __ATOMIC_RELAXED, __HIP_MEMORY_SCOPE_AGENT);
        }
        if (wave < 2) {
            f32x4 ra = {0.f, 0.f, 0.f, 0.f};
#pragma unroll
            for (int kt = 0; kt < 8; ++kt)
                ra = __builtin_amdgcn_mfma_f32_16x16x32_bf16(*(const bf16x8*)(aBase + (16+kt)*512), rwf[kt], ra, 0, 0, 0);
#pragma unroll
            for (int r = 0; r < 4; ++r)
                rsx[zMt*16 + lq*4 + r][lm] = ra[r];
        } else if (wave == 3) {
            for (;;) {
                unsigned v = __hip_atomic_load(flagsH + (lane & 31), __ATOMIC_RELAXED, __HIP_MEMORY_SCOPE_AGENT);
                if (__ballot(v < want) == 0ULL) break;
                __builtin_amdgcn_s_sleep(1);
            }
            asm volatile("" ::: "memory");
        }
        __syncthreads();                                   // S3

        // ---- stage h_t -> frag region kt 0..7 (all threads) ----
        {
            unsigned long long* src = Hbuf + (size_t)(pc*2 + d)*2048;
#pragma unroll
            for (int i = 0; i < 4; ++i) {
                int b_ = (tid & 7) + 8*i;
                int j  = tid >> 3;
                unsigned long long v0 = __hip_atomic_load(src + (size_t)b_*64 + j*2,     __ATOMIC_RELAXED, __HIP_MEMORY_SCOPE_AGENT);
                unsigned long long v1 = __hip_atomic_load(src + (size_t)b_*64 + j*2 + 1, __ATOMIC_RELAXED, __HIP_MEMORY_SCOPE_AGENT);
                u64x2 pk; pk.x = v0; pk.y = v1;
                *(u64x2*)FRAG_PTR(b_ >> 4, (j >> 2), j & 3, b_ & 15) = pk;
            }
        }
        __syncthreads();                                   // S4

        // ---- rsh (waves2,3) ; stage x_{t+1} (waves0,1) ----
        if (wave >= 2) {
            f32x4 ra = {0.f, 0.f, 0.f, 0.f};
#pragma unroll
            for (int kt = 0; kt < 8; ++kt)
                ra = __builtin_amdgcn_mfma_f32_16x16x32_bf16(*(const bf16x8*)(aBase + kt*512), rwf[kt], ra, 0, 0, 0);
#pragma unroll
            for (int r = 0; r < 4; ++r)
                rsh[zMt*16 + lq*4 + r][lm] = ra[r];
        } else if (t + 1 < Ss) {
            int txn = d ? (Ss - 2 - t) : (t + 1);
#pragma unroll
            for (int i = 0; i < 8; ++i) {
                int b_ = (tid & 7) + 8*(i >> 1);
                int j  = (tid >> 3) + 16*(i & 1);
                const float* xp = inputs + (((size_t)b_*Ss + txn) << 8) + j*8;
                float4 v0 = *(const float4*)xp;
                float4 v1 = *(const float4*)(xp + 4);
                u64x2 pk; pk.x = pack4(v0); pk.y = pack4(v1);
                *(u64x2*)FRAG_PTR(b_ >> 4, 16 + (j >> 2), j & 3, b_ & 15) = pk;
            }
        }
        __syncthreads();                                   // S5

        // ---- s update ----
        {
#pragma unroll
            for (int kk = 0; kk < 2; ++kk) {
                float rv = rsx[eb][kk*8+ej] + rsh[eb][kk*8+ej] + (kk ? brr1 : brr0);
                float rr = sigm(rv);
                float so = sS2[kk][eb][ej];
                float sn = rr*so + (1.f - rr)*cu_;
                float su = m_*sn + (1.f - m_)*so;
                sS2[kk][eb][ej] = su;
                out[33554432 + (((size_t)kk*1024 + tx)*32 + eb)*512 + d*256 + gj] = su;
                if (kk == idxv) sSb[tid] = f2bf(su);
            }
        }
        __syncthreads();                                   // S6

        // ---- publish s[idx] (wave0) ; poll flagsS (wave3) ----
        if (wave == 0) {
            unsigned long long pk = *(const unsigned long long*)&sSb[lane*4];
            __hip_atomic_store(Sbuf + (size_t)(pc*2 + d)*2048 + (size_t)(lane>>1)*64 + g*2 + (lane&1),
                               pk, __ATOMIC_RELAXED, __HIP_MEMORY_SCOPE_AGENT);
            asm volatile("s_waitcnt vmcnt(0)" ::: "memory");
            if (lane == 0)
                __hip_atomic_store(flagsS + g, want, __ATOMIC_RELAXED, __HIP_MEMORY_SCOPE_AGENT);
        } else if (wave == 3 && t + 1 < Ss) {
            for (;;) {
                unsigned v = __hip_atomic_load(flagsS + (lane & 31), __ATOMIC_RELAXED, __HIP_MEMORY_SCOPE_AGENT);
                if (__ballot(v < want) == 0ULL) break;
                __builtin_amdgcn_s_sleep(1);
            }
            asm volatile("" ::: "memory");
        }
        __syncthreads();                                   // S7

        // ---- stage s_t -> frag region kt 8..15 ----
        if (t + 1 < Ss) {
            unsigned long long* src = Sbuf + (size_t)(pc*2 + d)*2048;
#pragma unroll
            for (int i = 0; i < 4; ++i) {
                int b_ = (tid & 7) + 8*i;
                int j  = tid >> 3;
                unsigned long long v0 = __hip_atomic_load(src + (size_t)b_*64 + j*2,     __ATOMIC_RELAXED, __HIP_MEMORY_SCOPE_AGENT);
                unsigned long long v1 = __hip_atomic_load(src + (size_t)b_*64 + j*2 + 1, __ATOMIC_RELAXED, __HIP_MEMORY_SCOPE_AGENT);
                u64x2 pk; pk.x = v0; pk.y = v1;
                *(u64x2*)FRAG_PTR(b_ >> 4, 8 + (j >> 2), j & 3, b_ & 15) = pk;
            }
            __syncthreads();                               // S8
        }
    }
}

// ---------------------------------------------------------------------------
extern "C" void kernel_launch(void* const* d_in, const int* in_sizes, int n_in,
                              void* d_out, int out_size, void* d_ws, size_t ws_size,
                              hipStream_t stream) {
    const float* inputs = (const float*)d_in[0];
    const float* mask_  = (const float*)d_in[1];
    const float* Wx0  = (const float*)d_in[2];
    const float* Wh0  = (const float*)d_in[3];
    const float* Ws0  = (const float*)d_in[4];
    const float* b0   = (const float*)d_in[5];
    const float* Wrx0 = (const float*)d_in[6];
    const float* Wrh0 = (const float*)d_in[7];
    const float* br0  = (const float*)d_in[8];
    const float* Wx1  = (const float*)d_in[9];
    const float* Wh1  = (const float*)d_in[10];
    const float* Ws1  = (const float*)d_in[11];
    const float* b1   = (const float*)d_in[12];
    const float* Wrx1 = (const float*)d_in[13];
    const float* Wrh1 = (const float*)d_in[14];
    const float* br1  = (const float*)d_in[15];
    const int*   idxp = (const int*)d_in[16];
    unsigned char* ws = (unsigned char*)d_ws;

    hipLaunchKernelGGL(prepass, dim3(512), dim3(256), 0, stream,
                       Wx0, Wh0, Ws0, Wx1, Wh1, Ws1, Wrx0, Wrh0, Wrx1, Wrh1, ws);
    hipLaunchKernelGGL(bislstm, dim3(64), dim3(256), 0, stream,
                       inputs, mask_, b0, b1, br0, br1, idxp,
                       ws, (float*)d_out);
}